// Round 1
// baseline (1846.860 us; speedup 1.0000x reference)
//
#include <hip/hip_runtime.h>
#include <math.h>

#define B_   4
#define S_   2048
#define E_   256
#define H_   8
#define DK_  32
#define NROWS (B_*S_)   // 8192

// ---------------------------------------------------------------------------
// GEMM: Y[n,m] = sum_k X[n,k]*W[m,k] + bias[m]
// mode 0: Y stored at [n*M + m]                      (plain row-major)
// mode 1: Y stored at [((b*H + h)*S + s)*DK + d]     (head-split [B,H,S,DK])
// ---------------------------------------------------------------------------
__global__ __launch_bounds__(256)
void gemm_xt(const float* __restrict__ X, const float* __restrict__ W,
             const float* __restrict__ bias, float* __restrict__ Y,
             int N, int K, int M, int mode)
{
    __shared__ float sX[16][17];
    __shared__ float sW[16][17];
    const int tx = threadIdx.x, ty = threadIdx.y;
    const int n  = blockIdx.y * 16 + ty;
    const int m0 = blockIdx.x * 16;
    const int m  = m0 + tx;
    float acc = 0.f;
    for (int k0 = 0; k0 < K; k0 += 16) {
        sX[ty][tx] = X[(size_t)n * K + k0 + tx];
        sW[ty][tx] = W[(size_t)(m0 + ty) * K + k0 + tx];
        __syncthreads();
        #pragma unroll
        for (int kk = 0; kk < 16; kk++)
            acc = fmaf(sX[ty][kk], sW[tx][kk], acc);
        __syncthreads();
    }
    acc += bias[m];
    if (mode == 0) {
        Y[(size_t)n * M + m] = acc;
    } else {
        const int b = n / S_, s = n % S_;
        const int h = m / DK_, d = m % DK_;
        Y[(((size_t)(b * H_ + h)) * S_ + s) * DK_ + d] = acc;
    }
}

// ---------------------------------------------------------------------------
// Block-wide reductions (256 threads)
// ---------------------------------------------------------------------------
__device__ __forceinline__ float block_reduce_max(float v, float* sRed)
{
    const int t = threadIdx.x;
    sRed[t] = v; __syncthreads();
    #pragma unroll
    for (int off = 128; off > 0; off >>= 1) {
        if (t < off) sRed[t] = fmaxf(sRed[t], sRed[t + off]);
        __syncthreads();
    }
    float r = sRed[0]; __syncthreads();
    return r;
}

__device__ __forceinline__ float block_reduce_sum(float v, float* sRed)
{
    const int t = threadIdx.x;
    sRed[t] = v; __syncthreads();
    #pragma unroll
    for (int off = 128; off > 0; off >>= 1) {
        if (t < off) sRed[t] = sRed[t] + sRed[t + off];
        __syncthreads();
    }
    float r = sRed[0]; __syncthreads();
    return r;
}

// ---------------------------------------------------------------------------
// Attention: one block per (b,h,i) query row.
//   s_j   = (q_i . k_j) / sqrt(dk)                 j <= i
//   p     = softmax(s)                              (disttotal == 1 exactly)
//   cum_j = prefix_sum(p)
//   dist  = sqrt(max((1 - cum_j)*(i-j), 0))
//   eff   = clip(exp(-softplus(gamma_h)*dist), 1e-5, 1e5)
//   attn  = softmax(s * eff)   (masked j>i -> -inf)
//   out_i = sum_j attn_j * v_j      -> written in concat [B,S,E] layout
// ---------------------------------------------------------------------------
__global__ __launch_bounds__(256)
void attn_rows(const float* __restrict__ Qh, const float* __restrict__ Kh,
               const float* __restrict__ Vh, const float* __restrict__ gammas,
               float* __restrict__ Out)
{
    __shared__ float sS[S_];      // score row (later: decayed scores)
    __shared__ float sP[S_];      // exp row / prefix sums / attn weights
    __shared__ float sRed[256];
    __shared__ float sScan[256];
    __shared__ float sQ[DK_];

    const int tid = threadIdx.x;
    const int idx = blockIdx.x;
    const int bh  = idx / S_;       // consecutive blocks share (b,h) -> K/V hot in L2
    const int i   = idx % S_;
    const int h   = bh % H_;
    const int b   = bh / H_;
    const int L   = i + 1;

    const float* Kb   = Kh + (size_t)bh * S_ * DK_;
    const float* Vb   = Vh + (size_t)bh * S_ * DK_;
    const float* qrow = Qh + ((size_t)bh * S_ + i) * DK_;

    if (tid < DK_) sQ[tid] = qrow[tid];
    __syncthreads();

    // gamma_h = -softplus(gammas[h]), numerically safe
    const float g  = gammas[h];
    const float sp = (g > 20.f) ? g : log1pf(expf(g));
    const float gamma = -sp;

    // ---- pass 1: scores -------------------------------------------------
    const float4* sQ4 = reinterpret_cast<const float4*>(sQ);
    const float4 q0 = sQ4[0], q1 = sQ4[1], q2 = sQ4[2], q3 = sQ4[3];
    const float4 q4 = sQ4[4], q5 = sQ4[5], q6 = sQ4[6], q7 = sQ4[7];

    float lmax = -3.0e38f;
    for (int j = tid; j < L; j += 256) {
        const float4* kr = reinterpret_cast<const float4*>(Kb + (size_t)j * DK_);
        float4 k0 = kr[0], k1 = kr[1], k2 = kr[2], k3 = kr[3];
        float4 k4 = kr[4], k5 = kr[5], k6 = kr[6], k7 = kr[7];
        float acc = 0.f;
        acc = fmaf(q0.x,k0.x,acc); acc = fmaf(q0.y,k0.y,acc); acc = fmaf(q0.z,k0.z,acc); acc = fmaf(q0.w,k0.w,acc);
        acc = fmaf(q1.x,k1.x,acc); acc = fmaf(q1.y,k1.y,acc); acc = fmaf(q1.z,k1.z,acc); acc = fmaf(q1.w,k1.w,acc);
        acc = fmaf(q2.x,k2.x,acc); acc = fmaf(q2.y,k2.y,acc); acc = fmaf(q2.z,k2.z,acc); acc = fmaf(q2.w,k2.w,acc);
        acc = fmaf(q3.x,k3.x,acc); acc = fmaf(q3.y,k3.y,acc); acc = fmaf(q3.z,k3.z,acc); acc = fmaf(q3.w,k3.w,acc);
        acc = fmaf(q4.x,k4.x,acc); acc = fmaf(q4.y,k4.y,acc); acc = fmaf(q4.z,k4.z,acc); acc = fmaf(q4.w,k4.w,acc);
        acc = fmaf(q5.x,k5.x,acc); acc = fmaf(q5.y,k5.y,acc); acc = fmaf(q5.z,k5.z,acc); acc = fmaf(q5.w,k5.w,acc);
        acc = fmaf(q6.x,k6.x,acc); acc = fmaf(q6.y,k6.y,acc); acc = fmaf(q6.z,k6.z,acc); acc = fmaf(q6.w,k6.w,acc);
        acc = fmaf(q7.x,k7.x,acc); acc = fmaf(q7.y,k7.y,acc); acc = fmaf(q7.z,k7.z,acc); acc = fmaf(q7.w,k7.w,acc);
        acc *= 0.17677669529663687f;   // 1/sqrt(32)
        sS[j] = acc;
        lmax = fmaxf(lmax, acc);
    }
    const float m1 = block_reduce_max(lmax, sRed);

    // ---- softmax #1 ------------------------------------------------------
    float lsum = 0.f;
    for (int j = tid; j < L; j += 256) {
        float p = expf(sS[j] - m1);
        sP[j] = p;
        lsum += p;
    }
    const float Z = block_reduce_sum(lsum, sRed);
    const float invZ = 1.0f / Z;

    // ---- inclusive prefix scan of sP[0..L-1] ----------------------------
    // chunked: thread t owns [t*8, t*8+8)
    const int j0 = tid * 8;
    float run = 0.f;
    #pragma unroll
    for (int u = 0; u < 8; u++) {
        int j = j0 + u;
        if (j < L) { run += sP[j]; sP[j] = run; }
    }
    sScan[tid] = run;
    __syncthreads();
    // Hillis-Steele inclusive scan over 256 chunk totals
    for (int off = 1; off < 256; off <<= 1) {
        float v = (tid >= off) ? sScan[tid - off] : 0.f;
        __syncthreads();
        sScan[tid] += v;
        __syncthreads();
    }
    const float excl = sScan[tid] - run;
    #pragma unroll
    for (int u = 0; u < 8; u++) {
        int j = j0 + u;
        if (j < L) sP[j] += excl;
    }
    __syncthreads();

    // ---- decay + softmax #2 ---------------------------------------------
    float lmax2 = -3.0e38f;
    for (int j = tid; j < L; j += 256) {
        float cum  = sP[j] * invZ;               // distcum / disttotal (=1)
        float rest = fmaxf(1.0f - cum, 0.f);
        float pos  = (float)(i - j);             // |i-j| for j<=i
        float dist = sqrtf(rest * pos);
        float eff  = expf(gamma * dist);
        eff = fminf(fmaxf(eff, 1e-5f), 1e5f);
        float s2 = sS[j] * eff;
        sS[j] = s2;
        lmax2 = fmaxf(lmax2, s2);
    }
    const float m2 = block_reduce_max(lmax2, sRed);

    float lsum2 = 0.f;
    for (int j = tid; j < L; j += 256) {
        float p = expf(sS[j] - m2);
        sP[j] = p;
        lsum2 += p;
    }
    const float Z2 = block_reduce_sum(lsum2, sRed);
    const float invZ2 = 1.0f / Z2;

    // ---- attn @ V, coalesced: lane -> head dim, group -> j stripe -------
    const int d = tid & 31;
    const int grp = tid >> 5;                    // 8 groups
    float acc = 0.f;
    for (int j = grp; j < L; j += 8) {
        acc = fmaf(sP[j], Vb[(size_t)j * DK_ + d], acc);
    }
    sScan[tid] = acc;                            // [8][32]
    __syncthreads();
    if (tid < DK_) {
        float tot = 0.f;
        #pragma unroll
        for (int gg = 0; gg < 8; gg++) tot += sScan[gg * 32 + tid];
        // concat layout [B,S,E]
        Out[((size_t)(b * S_ + i)) * E_ + h * DK_ + tid] = tot * invZ2;
    }
}

// ---------------------------------------------------------------------------
extern "C" void kernel_launch(void* const* d_in, const int* in_sizes, int n_in,
                              void* d_out, int out_size, void* d_ws, size_t ws_size,
                              hipStream_t stream)
{
    const float* q      = (const float*)d_in[0];
    const float* k      = (const float*)d_in[1];
    const float* v      = (const float*)d_in[2];
    // d_in[3] = mask (causal, known analytically; unused)
    const float* Wq     = (const float*)d_in[4];
    const float* bq     = (const float*)d_in[5];
    const float* Wk     = (const float*)d_in[6];
    const float* bk     = (const float*)d_in[7];
    const float* Wv     = (const float*)d_in[8];
    const float* bv     = (const float*)d_in[9];
    const float* Wo     = (const float*)d_in[10];
    const float* bo     = (const float*)d_in[11];
    const float* gammas = (const float*)d_in[12];
    float* out = (float*)d_out;

    const size_t headN = (size_t)B_ * H_ * S_ * DK_;   // 8M floats
    float* qh     = (float*)d_ws;
    float* kh     = qh + headN;
    float* vh     = kh + headN;
    float* concat = vh + headN;                        // [B,S,E] fp32

    dim3 blk(16, 16);
    dim3 grd(E_ / 16, NROWS / 16);
    gemm_xt<<<grd, blk, 0, stream>>>(q, Wq, bq, qh, NROWS, E_, E_, 1);
    gemm_xt<<<grd, blk, 0, stream>>>(k, Wk, bk, kh, NROWS, E_, E_, 1);
    gemm_xt<<<grd, blk, 0, stream>>>(v, Wv, bv, vh, NROWS, E_, E_, 1);

    attn_rows<<<B_ * H_ * S_, 256, 0, stream>>>(qh, kh, vh, gammas, concat);

    gemm_xt<<<grd, blk, 0, stream>>>(concat, Wo, bo, out, NROWS, E_, E_, 0);
}

// Round 2
// 1699.140 us; speedup vs baseline: 1.0869x; 1.0869x over previous
//
#include <hip/hip_runtime.h>
#include <math.h>

#define B_   4
#define S_   2048
#define E_   256
#define H_   8
#define DK_  32
#define NROWS (B_*S_)   // 8192

// ---------------------------------------------------------------------------
// GEMM: Y[n,m] = sum_k X[n,k]*W[m,k] + bias[m]
// 64x64 tile, 256 threads, 4x4 micro-tile per thread, LDS stored [k][n]/[k][m]
// so fragment reads are ds_read_b128 (conflict-free / 2-way only).
// mode 0: Y[n*E + m] ; mode 1: head-split [B,H,S,DK]
// ---------------------------------------------------------------------------
__global__ __launch_bounds__(256)
void gemm64(const float* __restrict__ X, const float* __restrict__ W,
            const float* __restrict__ bias, float* __restrict__ Y, int mode)
{
    __shared__ float sA[16][64];   // [k][n]
    __shared__ float sB[16][64];   // [k][m]
    const int tid = threadIdx.x;
    const int tx = tid & 15, ty = tid >> 4;
    const int n0 = blockIdx.y * 64, m0 = blockIdx.x * 64;
    const int lr = tid >> 2;          // load row 0..63
    const int lc = (tid & 3) * 4;     // load col 0,4,8,12

    float acc[4][4] = {};
    for (int k0 = 0; k0 < E_; k0 += 16) {
        const float4 ax = *(const float4*)(X + (size_t)(n0 + lr) * E_ + k0 + lc);
        const float4 wx = *(const float4*)(W + (size_t)(m0 + lr) * E_ + k0 + lc);
        __syncthreads();               // previous iter's reads done
        sA[lc+0][lr] = ax.x; sA[lc+1][lr] = ax.y; sA[lc+2][lr] = ax.z; sA[lc+3][lr] = ax.w;
        sB[lc+0][lr] = wx.x; sB[lc+1][lr] = wx.y; sB[lc+2][lr] = wx.z; sB[lc+3][lr] = wx.w;
        __syncthreads();
        #pragma unroll
        for (int kk = 0; kk < 16; kk++) {
            const float4 av = *(const float4*)&sA[kk][ty * 4];
            const float4 bv = *(const float4*)&sB[kk][tx * 4];
            const float ar[4] = {av.x, av.y, av.z, av.w};
            const float br[4] = {bv.x, bv.y, bv.z, bv.w};
            #pragma unroll
            for (int i = 0; i < 4; i++)
                #pragma unroll
                for (int j = 0; j < 4; j++)
                    acc[i][j] = fmaf(ar[i], br[j], acc[i][j]);
        }
    }

    const float4 bb = *(const float4*)(bias + m0 + tx * 4);
    const float badd[4] = {bb.x, bb.y, bb.z, bb.w};
    if (mode == 0) {
        #pragma unroll
        for (int i = 0; i < 4; i++) {
            const int n = n0 + ty * 4 + i;
            float4 o = {acc[i][0]+badd[0], acc[i][1]+badd[1], acc[i][2]+badd[2], acc[i][3]+badd[3]};
            *(float4*)(Y + (size_t)n * E_ + m0 + tx * 4) = o;
        }
    } else {
        const int m  = m0 + tx * 4;          // never crosses a 32-wide head boundary
        const int hh = m >> 5, d0 = m & 31;
        #pragma unroll
        for (int i = 0; i < 4; i++) {
            const int n = n0 + ty * 4 + i;
            const int bI = n >> 11, sI = n & (S_ - 1);
            float4 o = {acc[i][0]+badd[0], acc[i][1]+badd[1], acc[i][2]+badd[2], acc[i][3]+badd[3]};
            *(float4*)(Y + (((size_t)(bI * H_ + hh) * S_ + sI) * DK_ + d0)) = o;
        }
    }
}

// ---------------------------------------------------------------------------
// Shuffle-based block reductions: wave64 shfl tree + 4-wave LDS combine.
// ---------------------------------------------------------------------------
__device__ __forceinline__ float block_max(float v, float* sR)
{
    #pragma unroll
    for (int off = 32; off > 0; off >>= 1)
        v = fmaxf(v, __shfl_down(v, off));
    if ((threadIdx.x & 63) == 0) sR[threadIdx.x >> 6] = v;
    __syncthreads();
    float r = fmaxf(fmaxf(sR[0], sR[1]), fmaxf(sR[2], sR[3]));
    __syncthreads();
    return r;
}

__device__ __forceinline__ float block_sum(float v, float* sR)
{
    #pragma unroll
    for (int off = 32; off > 0; off >>= 1)
        v += __shfl_down(v, off);
    if ((threadIdx.x & 63) == 0) sR[threadIdx.x >> 6] = v;
    __syncthreads();
    float r = sR[0] + sR[1] + sR[2] + sR[3];
    __syncthreads();
    return r;
}

// ---------------------------------------------------------------------------
// Attention: one block per (b,h,i) row. Score row lives in REGISTERS
// (thread t owns j = t + 256u, u<8). Prefix scan = 8 wave-level shfl_up
// scans + one 32-float LDS combine (1 barrier). Only the final attn weights
// round-trip through LDS (conflict-free strided write, broadcast reads).
// ---------------------------------------------------------------------------
__global__ __launch_bounds__(256)
void attn_rows(const float* __restrict__ Qh, const float* __restrict__ Kh,
               const float* __restrict__ Vh, const float* __restrict__ gammas,
               float* __restrict__ Out)
{
    __shared__ float sP[S_];       // final (unnormalized) attn weights
    __shared__ float sWT[32];      // 8 segments x 4 wave totals
    __shared__ float sR[4];        // reduction scratch
    __shared__ float sAV[256];     // AV partials

    const int tid  = threadIdx.x;
    const int lane = tid & 63;
    const int wave = tid >> 6;
    const int idx  = blockIdx.x;
    const int bh   = idx >> 11;           // consecutive blocks share (b,h): K/V hot in L2
    const int i    = idx & (S_ - 1);
    const int h    = bh & (H_ - 1);
    const int b    = bh >> 3;
    const int L    = i + 1;

    const float* Kb   = Kh + (size_t)bh * S_ * DK_;
    const float* Vb   = Vh + (size_t)bh * S_ * DK_;
    const float* qrow = Qh + ((size_t)bh * S_ + i) * DK_;

    const float4* q4 = (const float4*)qrow;
    const float4 q0 = q4[0], q1 = q4[1], q2 = q4[2], q3 = q4[3];
    const float4 q4v = q4[4], q5 = q4[5], q6 = q4[6], q7 = q4[7];

    const float g     = gammas[h];
    const float gamma = -((g > 20.f) ? g : log1pf(expf(g)));

    // ---- pass 1: scores into registers ----------------------------------
    float s[8];
    float lmax = -3.0e38f;
    #pragma unroll
    for (int u = 0; u < 8; u++) {
        s[u] = -3.0e38f;
        if (u * 256 < L) {                       // uniform scalar branch
            const int j = u * 256 + tid;
            const float4* kr = (const float4*)(Kb + (size_t)j * DK_);
            const float4 k0 = kr[0], k1 = kr[1], k2 = kr[2], k3 = kr[3];
            const float4 k4 = kr[4], k5 = kr[5], k6 = kr[6], k7 = kr[7];
            float a = 0.f;
            a = fmaf(q0.x,k0.x,a); a = fmaf(q0.y,k0.y,a); a = fmaf(q0.z,k0.z,a); a = fmaf(q0.w,k0.w,a);
            a = fmaf(q1.x,k1.x,a); a = fmaf(q1.y,k1.y,a); a = fmaf(q1.z,k1.z,a); a = fmaf(q1.w,k1.w,a);
            a = fmaf(q2.x,k2.x,a); a = fmaf(q2.y,k2.y,a); a = fmaf(q2.z,k2.z,a); a = fmaf(q2.w,k2.w,a);
            a = fmaf(q3.x,k3.x,a); a = fmaf(q3.y,k3.y,a); a = fmaf(q3.z,k3.z,a); a = fmaf(q3.w,k3.w,a);
            a = fmaf(q4v.x,k4.x,a); a = fmaf(q4v.y,k4.y,a); a = fmaf(q4v.z,k4.z,a); a = fmaf(q4v.w,k4.w,a);
            a = fmaf(q5.x,k5.x,a); a = fmaf(q5.y,k5.y,a); a = fmaf(q5.z,k5.z,a); a = fmaf(q5.w,k5.w,a);
            a = fmaf(q6.x,k6.x,a); a = fmaf(q6.y,k6.y,a); a = fmaf(q6.z,k6.z,a); a = fmaf(q6.w,k6.w,a);
            a = fmaf(q7.x,k7.x,a); a = fmaf(q7.y,k7.y,a); a = fmaf(q7.z,k7.z,a); a = fmaf(q7.w,k7.w,a);
            a *= 0.17677669529663687f;           // 1/sqrt(32)
            if (j < L) { s[u] = a; lmax = fmaxf(lmax, a); }
        }
    }
    const float m1 = block_max(lmax, sR);

    // ---- softmax #1 (in registers) ---------------------------------------
    float p[8];
    float lsum = 0.f;
    #pragma unroll
    for (int u = 0; u < 8; u++) {
        if (u * 256 < L) { p[u] = expf(s[u] - m1); lsum += p[u]; }
        else p[u] = 0.f;
    }
    const float Z = block_sum(lsum, sR);
    const float invZ = 1.0f / Z;

    // ---- inclusive prefix scan: 8 wave scans + single LDS combine -------
    float vs[8];
    #pragma unroll
    for (int u = 0; u < 8; u++) {
        if (u * 256 < L) {
            float v = p[u];
            #pragma unroll
            for (int off = 1; off < 64; off <<= 1) {
                const float x = __shfl_up(v, off);
                if (lane >= off) v += x;
            }
            vs[u] = v;
            if (lane == 63) sWT[u * 4 + wave] = v;   // wave totals
        } else vs[u] = 0.f;
    }
    __syncthreads();

    float cum[8];
    {
        float segRun = 0.f;
        #pragma unroll
        for (int u = 0; u < 8; u++) {
            if (u * 256 < L) {
                float pre = 0.f, tot = 0.f;
                #pragma unroll
                for (int w = 0; w < 4; w++) {
                    const float t = sWT[u * 4 + w];
                    if (w < wave) pre += t;
                    tot += t;
                }
                cum[u] = vs[u] + pre + segRun;
                segRun += tot;
            } else cum[u] = 0.f;
        }
    }

    // ---- decay + second scores ------------------------------------------
    float lmax2 = -3.0e38f;
    #pragma unroll
    for (int u = 0; u < 8; u++) {
        if (u * 256 < L) {
            const int j = u * 256 + tid;
            const float rest = fmaxf(1.0f - cum[u] * invZ, 0.f);
            const float pos  = (float)(i - j);
            const float dist = sqrtf(fmaxf(rest * pos, 0.f));
            float eff = expf(gamma * dist);
            eff = fminf(fmaxf(eff, 1e-5f), 1e5f);
            const float s2 = (j < L) ? s[u] * eff : -3.0e38f;
            s[u] = s2;
            lmax2 = fmaxf(lmax2, s2);
        } else s[u] = -3.0e38f;
    }
    const float m2 = block_max(lmax2, sR);

    float lsum2 = 0.f;
    #pragma unroll
    for (int u = 0; u < 8; u++) {
        if (u * 256 < L) {
            const float p2 = expf(s[u] - m2);
            sP[u * 256 + tid] = p2;               // strided, conflict-free
            lsum2 += p2;
        }
    }
    const float Z2 = block_sum(lsum2, sR);        // barrier also publishes sP
    const float invZ2 = 1.0f / Z2;

    // ---- attn @ V: lane -> head dim, group -> j stripe ------------------
    const int d   = tid & 31;
    const int grp = tid >> 5;                     // 8 groups of 32
    float acc = 0.f;
    for (int j = grp; j < L; j += 8)
        acc = fmaf(sP[j], Vb[(size_t)j * DK_ + d], acc);
    sAV[tid] = acc;
    __syncthreads();
    if (tid < DK_) {
        float tot = 0.f;
        #pragma unroll
        for (int gg = 0; gg < 8; gg++) tot += sAV[gg * 32 + tid];
        Out[((size_t)(b * S_ + i)) * E_ + h * DK_ + tid] = tot * invZ2;
    }
}

// ---------------------------------------------------------------------------
extern "C" void kernel_launch(void* const* d_in, const int* in_sizes, int n_in,
                              void* d_out, int out_size, void* d_ws, size_t ws_size,
                              hipStream_t stream)
{
    const float* q      = (const float*)d_in[0];
    const float* k      = (const float*)d_in[1];
    const float* v      = (const float*)d_in[2];
    // d_in[3] = causal mask (analytic; unused)
    const float* Wq     = (const float*)d_in[4];
    const float* bq     = (const float*)d_in[5];
    const float* Wk     = (const float*)d_in[6];
    const float* bk     = (const float*)d_in[7];
    const float* Wv     = (const float*)d_in[8];
    const float* bv     = (const float*)d_in[9];
    const float* Wo     = (const float*)d_in[10];
    const float* bo     = (const float*)d_in[11];
    const float* gammas = (const float*)d_in[12];
    float* out = (float*)d_out;

    const size_t headN = (size_t)B_ * H_ * S_ * DK_;   // 2M floats each
    float* qh     = (float*)d_ws;
    float* kh     = qh + headN;
    float* vh     = kh + headN;
    float* concat = vh + headN;                        // [B,S,E] fp32

    dim3 blk(256);
    dim3 grd(E_ / 64, NROWS / 64);
    gemm64<<<grd, blk, 0, stream>>>(q, Wq, bq, qh, 1);
    gemm64<<<grd, blk, 0, stream>>>(k, Wk, bk, kh, 1);
    gemm64<<<grd, blk, 0, stream>>>(v, Wv, bv, vh, 1);

    attn_rows<<<B_ * H_ * S_, 256, 0, stream>>>(qh, kh, vh, gammas, concat);

    gemm64<<<grd, blk, 0, stream>>>(concat, Wo, bo, out, 0);
}

// Round 3
// 363.161 us; speedup vs baseline: 5.0855x; 4.6788x over previous
//
#include <hip/hip_runtime.h>
#include <math.h>

#define B_   4
#define S_   2048
#define E_   256
#define H_   8
#define DK_  32
#define NROWS (B_*S_)   // 8192

typedef __attribute__((ext_vector_type(8))) short  bf16x8;
typedef __attribute__((ext_vector_type(4))) float  f32x4;
typedef __attribute__((ext_vector_type(4))) unsigned short us4;

// ---------------------------------------------------------------------------
// GEMM: Y[n,m] = sum_k X[n,k]*W[m,k] + bias[m]   (unchanged from round 2)
// ---------------------------------------------------------------------------
__global__ __launch_bounds__(256)
void gemm64(const float* __restrict__ X, const float* __restrict__ W,
            const float* __restrict__ bias, float* __restrict__ Y, int mode)
{
    __shared__ float sA[16][64];   // [k][n]
    __shared__ float sB[16][64];   // [k][m]
    const int tid = threadIdx.x;
    const int tx = tid & 15, ty = tid >> 4;
    const int n0 = blockIdx.y * 64, m0 = blockIdx.x * 64;
    const int lr = tid >> 2;
    const int lc = (tid & 3) * 4;

    float acc[4][4] = {};
    for (int k0 = 0; k0 < E_; k0 += 16) {
        const float4 ax = *(const float4*)(X + (size_t)(n0 + lr) * E_ + k0 + lc);
        const float4 wx = *(const float4*)(W + (size_t)(m0 + lr) * E_ + k0 + lc);
        __syncthreads();
        sA[lc+0][lr] = ax.x; sA[lc+1][lr] = ax.y; sA[lc+2][lr] = ax.z; sA[lc+3][lr] = ax.w;
        sB[lc+0][lr] = wx.x; sB[lc+1][lr] = wx.y; sB[lc+2][lr] = wx.z; sB[lc+3][lr] = wx.w;
        __syncthreads();
        #pragma unroll
        for (int kk = 0; kk < 16; kk++) {
            const float4 av = *(const float4*)&sA[kk][ty * 4];
            const float4 bv = *(const float4*)&sB[kk][tx * 4];
            const float ar[4] = {av.x, av.y, av.z, av.w};
            const float br[4] = {bv.x, bv.y, bv.z, bv.w};
            #pragma unroll
            for (int i = 0; i < 4; i++)
                #pragma unroll
                for (int j = 0; j < 4; j++)
                    acc[i][j] = fmaf(ar[i], br[j], acc[i][j]);
        }
    }

    const float4 bb = *(const float4*)(bias + m0 + tx * 4);
    const float badd[4] = {bb.x, bb.y, bb.z, bb.w};
    if (mode == 0) {
        #pragma unroll
        for (int i = 0; i < 4; i++) {
            const int n = n0 + ty * 4 + i;
            float4 o = {acc[i][0]+badd[0], acc[i][1]+badd[1], acc[i][2]+badd[2], acc[i][3]+badd[3]};
            *(float4*)(Y + (size_t)n * E_ + m0 + tx * 4) = o;
        }
    } else {
        const int m  = m0 + tx * 4;
        const int hh = m >> 5, d0 = m & 31;
        #pragma unroll
        for (int i = 0; i < 4; i++) {
            const int n = n0 + ty * 4 + i;
            const int bI = n >> 11, sI = n & (S_ - 1);
            float4 o = {acc[i][0]+badd[0], acc[i][1]+badd[1], acc[i][2]+badd[2], acc[i][3]+badd[3]};
            *(float4*)(Y + (((size_t)(bI * H_ + hh) * S_ + sI) * DK_ + d0)) = o;
        }
    }
}

// ---------------------------------------------------------------------------
// bf16 helpers (round-to-nearest-even)
// ---------------------------------------------------------------------------
__device__ __forceinline__ unsigned short bf16_rne(float x)
{
    unsigned int u = __float_as_uint(x);
    unsigned int r = u + 0x7FFFu + ((u >> 16) & 1u);
    return (unsigned short)(r >> 16);
}
__device__ __forceinline__ float bf16_to_f(unsigned short h)
{
    return __uint_as_float(((unsigned int)h) << 16);
}

// ---------------------------------------------------------------------------
// Flash-style decay attention.
// One block = one (b,h) x 64 query rows. 4 waves, each owns a 16-row strip.
// K-tiles of 64 cols; pass A: online (m1,Z); pass B: recompute scores,
// prefix-scan cumsum, decay, online softmax-2 + MFMA PV.
// MFMA 16x16x32 bf16. QK^T in 3-term hi/lo split (~fp32 accuracy); PV bf16.
// Layouts (HW-verified per guide):
//   A-frag: A[m=lane&15][k=(lane>>4)*8+j]
//   B-frag: B[k=(lane>>4)*8+j][n=lane&15]
//   C/D   : col=lane&15, row=(lane>>4)*4+reg
// ---------------------------------------------------------------------------
#define KPAD 40   // ushort stride for K tiles  (80 B rows)
#define VPAD 72   // ushort stride for Vt/P     (144 B rows)

__global__ __launch_bounds__(256)
void attn_flash(const float* __restrict__ Qh, const float* __restrict__ Kh,
                const float* __restrict__ Vh, const float* __restrict__ gammas,
                float* __restrict__ Out)
{
    __shared__ __align__(16) unsigned short sKhi[64 * KPAD];
    __shared__ __align__(16) unsigned short sKlo[64 * KPAD];
    __shared__ __align__(16) unsigned short sVt [32 * VPAD];
    __shared__ __align__(16) unsigned short sP  [4][16 * VPAD];

    const int tid  = threadIdx.x;
    const int lane = tid & 63;
    const int w    = tid >> 6;
    const int lr   = lane & 15;        // A/B row-in-tile, D col
    const int lq   = lane >> 4;        // quad
    const int tq   = 31 - (blockIdx.x >> 5);   // longest blocks first
    const int bh   = blockIdx.x & 31;
    const int h    = bh & 7;
    const int b    = bh >> 3;
    const int i0   = tq * 64;

    const float* Qb = Qh + (size_t)bh * S_ * DK_;
    const float* Kb = Kh + (size_t)bh * S_ * DK_;
    const float* Vb = Vh + (size_t)bh * S_ * DK_;

    const float g     = gammas[h];
    const float gamma = -((g > 20.f) ? g : log1pf(__expf(g)));

    // ---- Q fragments (pre-scaled by 1/sqrt(dk), hi/lo split), direct load --
    bf16x8 qhi, qlo;
    {
        const int qrow = i0 + w * 16 + lr;
        const float4* qp = (const float4*)(Qb + (size_t)qrow * DK_ + lq * 8);
        const float4 qa = qp[0], qb4 = qp[1];
        float xs[8] = {qa.x, qa.y, qa.z, qa.w, qb4.x, qb4.y, qb4.z, qb4.w};
        #pragma unroll
        for (int e = 0; e < 8; e++) {
            float x = xs[e] * 0.17677669529663687f;
            unsigned short hb = bf16_rne(x);
            qhi[e] = (short)hb;
            qlo[e] = (short)bf16_rne(x - bf16_to_f(hb));
        }
    }

    // ======================= PASS A: m1, Z ================================
    float m1v[4], z1v[4];
    #pragma unroll
    for (int r = 0; r < 4; r++) { m1v[r] = -3.0e38f; z1v[r] = 0.f; }

    for (int jt = 0; jt <= tq; jt++) {
        const int j0 = jt * 64;
        // stage K tile -> hi/lo bf16 LDS
        #pragma unroll
        for (int u = 0; u < 2; u++) {
            const int vi  = u * 256 + tid;          // float4 index 0..511
            const int row = vi >> 3, c4 = vi & 7;
            const float4 kv = *(const float4*)(Kb + (size_t)j0 * DK_ + vi * 4);
            float xs[4] = {kv.x, kv.y, kv.z, kv.w};
            us4 h4, l4;
            #pragma unroll
            for (int c = 0; c < 4; c++) {
                unsigned short hb = bf16_rne(xs[c]);
                h4[c] = hb;
                l4[c] = bf16_rne(xs[c] - bf16_to_f(hb));
            }
            *(us4*)&sKhi[row * KPAD + c4 * 4] = h4;
            *(us4*)&sKlo[row * KPAD + c4 * 4] = l4;
        }
        __syncthreads();

        f32x4 acc[4];
        #pragma unroll
        for (int t = 0; t < 4; t++) {
            const int krow = t * 16 + lr;
            const bf16x8 khi = *(const bf16x8*)&sKhi[krow * KPAD + lq * 8];
            const bf16x8 klo = *(const bf16x8*)&sKlo[krow * KPAD + lq * 8];
            f32x4 a = {0.f, 0.f, 0.f, 0.f};
            a = __builtin_amdgcn_mfma_f32_16x16x32_bf16(qlo, khi, a, 0, 0, 0);
            a = __builtin_amdgcn_mfma_f32_16x16x32_bf16(qhi, klo, a, 0, 0, 0);
            a = __builtin_amdgcn_mfma_f32_16x16x32_bf16(qhi, khi, a, 0, 0, 0);
            acc[t] = a;
        }
        if (jt == tq) {            // diagonal tile: mask j > i
            #pragma unroll
            for (int t = 0; t < 4; t++)
                #pragma unroll
                for (int r = 0; r < 4; r++) {
                    const int irow = i0 + w * 16 + lq * 4 + r;
                    const int j    = j0 + t * 16 + lr;
                    if (j > irow) acc[t][r] = -3.0e38f;
                }
        }
        #pragma unroll
        for (int r = 0; r < 4; r++) {
            float tm = fmaxf(fmaxf(acc[0][r], acc[1][r]), fmaxf(acc[2][r], acc[3][r]));
            #pragma unroll
            for (int off = 1; off < 16; off <<= 1)
                tm = fmaxf(tm, __shfl_xor(tm, off));
            const float mnew = fmaxf(m1v[r], tm);
            const float al   = __expf(m1v[r] - mnew);
            float rs = 0.f;
            #pragma unroll
            for (int t = 0; t < 4; t++) rs += __expf(acc[t][r] - mnew);
            #pragma unroll
            for (int off = 1; off < 16; off <<= 1)
                rs += __shfl_xor(rs, off);
            z1v[r] = z1v[r] * al + rs;
            m1v[r] = mnew;
        }
        __syncthreads();
    }

    float invZ[4];
    #pragma unroll
    for (int r = 0; r < 4; r++) invZ[r] = 1.0f / z1v[r];

    // ======================= PASS B: decay + softmax2 + PV ================
    float m2v[4], z2v[4], carry[4];
    f32x4 O0 = {0.f,0.f,0.f,0.f}, O1 = {0.f,0.f,0.f,0.f};
    #pragma unroll
    for (int r = 0; r < 4; r++) { m2v[r] = -3.0e38f; z2v[r] = 0.f; carry[r] = 0.f; }

    unsigned short* sPw = &sP[w][0];

    for (int jt = 0; jt <= tq; jt++) {
        const int j0 = jt * 64;
        // stage K (hi/lo) + V (transposed, bf16)
        #pragma unroll
        for (int u = 0; u < 2; u++) {
            const int vi  = u * 256 + tid;
            const int row = vi >> 3, c4 = vi & 7;
            const float4 kv = *(const float4*)(Kb + (size_t)j0 * DK_ + vi * 4);
            const float4 vv = *(const float4*)(Vb + (size_t)j0 * DK_ + vi * 4);
            float xs[4] = {kv.x, kv.y, kv.z, kv.w};
            float vs[4] = {vv.x, vv.y, vv.z, vv.w};
            us4 h4, l4;
            #pragma unroll
            for (int c = 0; c < 4; c++) {
                unsigned short hb = bf16_rne(xs[c]);
                h4[c] = hb;
                l4[c] = bf16_rne(xs[c] - bf16_to_f(hb));
                sVt[(c4 * 4 + c) * VPAD + row] = bf16_rne(vs[c]);
            }
            *(us4*)&sKhi[row * KPAD + c4 * 4] = h4;
            *(us4*)&sKlo[row * KPAD + c4 * 4] = l4;
        }
        __syncthreads();

        // scores (same as pass A)
        f32x4 acc[4];
        #pragma unroll
        for (int t = 0; t < 4; t++) {
            const int krow = t * 16 + lr;
            const bf16x8 khi = *(const bf16x8*)&sKhi[krow * KPAD + lq * 8];
            const bf16x8 klo = *(const bf16x8*)&sKlo[krow * KPAD + lq * 8];
            f32x4 a = {0.f, 0.f, 0.f, 0.f};
            a = __builtin_amdgcn_mfma_f32_16x16x32_bf16(qlo, khi, a, 0, 0, 0);
            a = __builtin_amdgcn_mfma_f32_16x16x32_bf16(qhi, klo, a, 0, 0, 0);
            a = __builtin_amdgcn_mfma_f32_16x16x32_bf16(qhi, khi, a, 0, 0, 0);
            acc[t] = a;
        }
        if (jt == tq) {
            #pragma unroll
            for (int t = 0; t < 4; t++)
                #pragma unroll
                for (int r = 0; r < 4; r++) {
                    const int irow = i0 + w * 16 + lq * 4 + r;
                    const int j    = j0 + t * 16 + lr;
                    if (j > irow) acc[t][r] = -3.0e38f;
                }
        }

        // p1, row prefix-scan (cumsum), decay -> s2 (in place in acc)
        #pragma unroll
        for (int r = 0; r < 4; r++) {
            const int irow = i0 + w * 16 + lq * 4 + r;
            float base = carry[r];
            #pragma unroll
            for (int t = 0; t < 4; t++) {
                const int j = j0 + t * 16 + lr;
                float v = __expf(acc[t][r] - m1v[r]) * invZ[r];   // p1 (0 if masked)
                #pragma unroll
                for (int off = 1; off < 16; off <<= 1) {
                    const float x = __shfl_up(v, off);
                    if ((lane & 15) >= off) v += x;
                }
                const float tot = __shfl(v, lane | 15);
                const float cum = v + base;
                base += tot;
                const float rest = fmaxf(1.0f - cum, 0.f);
                const float posf = (float)(irow - j);
                const float dist = sqrtf(fmaxf(rest * posf, 0.f));
                float eff = __expf(gamma * dist);
                eff = fminf(fmaxf(eff, 1e-5f), 1e5f);
                acc[t][r] = acc[t][r] * eff;                      // s2
            }
            carry[r] = base;
        }

        // online softmax-2 + P write (bf16, C-layout -> LDS rows)
        #pragma unroll
        for (int r = 0; r < 4; r++) {
            float tm = fmaxf(fmaxf(acc[0][r], acc[1][r]), fmaxf(acc[2][r], acc[3][r]));
            #pragma unroll
            for (int off = 1; off < 16; off <<= 1)
                tm = fmaxf(tm, __shfl_xor(tm, off));
            const float mnew = fmaxf(m2v[r], tm);
            const float al   = __expf(m2v[r] - mnew);
            O0[r] *= al; O1[r] *= al;
            float p2[4], rs = 0.f;
            #pragma unroll
            for (int t = 0; t < 4; t++) { p2[t] = __expf(acc[t][r] - mnew); rs += p2[t]; }
            #pragma unroll
            for (int off = 1; off < 16; off <<= 1)
                rs += __shfl_xor(rs, off);
            z2v[r] = z2v[r] * al + rs;
            m2v[r] = mnew;
            const int m = lq * 4 + r;
            #pragma unroll
            for (int t = 0; t < 4; t++)
                sPw[m * VPAD + t * 16 + lr] = bf16_rne(p2[t]);
        }

        // PV: P (A-frag, wave-local LDS) x Vt (B-frag) -> O (C-layout)
        #pragma unroll
        for (int kc = 0; kc < 2; kc++) {
            const bf16x8 pa = *(const bf16x8*)&sPw[lr * VPAD + kc * 32 + lq * 8];
            const bf16x8 v0 = *(const bf16x8*)&sVt[(lr)      * VPAD + kc * 32 + lq * 8];
            const bf16x8 v1 = *(const bf16x8*)&sVt[(16 + lr) * VPAD + kc * 32 + lq * 8];
            O0 = __builtin_amdgcn_mfma_f32_16x16x32_bf16(pa, v0, O0, 0, 0, 0);
            O1 = __builtin_amdgcn_mfma_f32_16x16x32_bf16(pa, v1, O1, 0, 0, 0);
        }
        __syncthreads();
    }

    // ---- epilogue: normalize, write concat [B,S,E] -----------------------
    #pragma unroll
    for (int r = 0; r < 4; r++) {
        const float inv  = 1.0f / z2v[r];
        const int   irow = i0 + w * 16 + lq * 4 + r;
        float* orow = Out + ((size_t)(b * S_ + irow)) * E_ + h * DK_;
        orow[lr]      = O0[r] * inv;
        orow[16 + lr] = O1[r] * inv;
    }
}

// ---------------------------------------------------------------------------
extern "C" void kernel_launch(void* const* d_in, const int* in_sizes, int n_in,
                              void* d_out, int out_size, void* d_ws, size_t ws_size,
                              hipStream_t stream)
{
    const float* q      = (const float*)d_in[0];
    const float* k      = (const float*)d_in[1];
    const float* v      = (const float*)d_in[2];
    // d_in[3] = causal mask (analytic; unused)
    const float* Wq     = (const float*)d_in[4];
    const float* bq     = (const float*)d_in[5];
    const float* Wk     = (const float*)d_in[6];
    const float* bk     = (const float*)d_in[7];
    const float* Wv     = (const float*)d_in[8];
    const float* bv     = (const float*)d_in[9];
    const float* Wo     = (const float*)d_in[10];
    const float* bo     = (const float*)d_in[11];
    const float* gammas = (const float*)d_in[12];
    float* out = (float*)d_out;

    const size_t headN = (size_t)B_ * H_ * S_ * DK_;   // 2M floats each
    float* qh     = (float*)d_ws;
    float* kh     = qh + headN;
    float* vh     = kh + headN;
    float* concat = vh + headN;                        // [B,S,E] fp32

    dim3 blk(256);
    dim3 grd(E_ / 64, NROWS / 64);
    gemm64<<<grd, blk, 0, stream>>>(q, Wq, bq, qh, 1);
    gemm64<<<grd, blk, 0, stream>>>(k, Wk, bk, kh, 1);
    gemm64<<<grd, blk, 0, stream>>>(v, Wv, bv, vh, 1);

    attn_flash<<<B_ * H_ * (S_ / 64), 256, 0, stream>>>(qh, kh, vh, gammas, concat);

    gemm64<<<grd, blk, 0, stream>>>(concat, Wo, bo, out, 0);
}